// Round 1
// baseline (475.516 us; speedup 1.0000x reference)
//
#include <hip/hip_runtime.h>
#include <stdint.h>

#define SEQ 2048
#define DM  1024
#define NH  16
#define HD  64
#define FFD 4096
#define TOK 8192
#define KPAD 88

typedef __bf16 bf16x8 __attribute__((ext_vector_type(8)));
typedef float  f32x4  __attribute__((ext_vector_type(4)));
typedef unsigned short u16x8 __attribute__((ext_vector_type(8)));
typedef unsigned short u16x4 __attribute__((ext_vector_type(4)));

__device__ __forceinline__ unsigned short f2bf(float f) {
  unsigned u = __builtin_bit_cast(unsigned, f);
  u += 0x7fffu + ((u >> 16) & 1u);
  return (unsigned short)(u >> 16);
}
__device__ __forceinline__ float bf2f(unsigned short h) {
  return __builtin_bit_cast(float, ((unsigned)h) << 16);
}
__device__ __forceinline__ f32x4 mfma16(bf16x8 a, bf16x8 b, f32x4 c) {
  return __builtin_amdgcn_mfma_f32_16x16x32_bf16(a, b, c, 0, 0, 0);
}
__device__ __forceinline__ void gld_lds16(void* lds, const void* g) {
  __builtin_amdgcn_global_load_lds((__attribute__((address_space(1))) void*)g,
                                   (__attribute__((address_space(3))) void*)lds,
                                   16, 0, 0);
}

// ---------------- elementwise casts ----------------
__global__ __launch_bounds__(256) void concat_cast(
    const float* __restrict__ kq, const float* __restrict__ v,
    unsigned short* __restrict__ X) {
  int i = (blockIdx.x * 256 + threadIdx.x) * 4;   // over TOK*DM
  int tkn = i >> 10;
  int c = i & 1023;
  const float* s = (c < 512) ? (kq + (size_t)tkn * 512 + c)
                             : (v  + (size_t)tkn * 512 + (c - 512));
  f32x4 f = *(const f32x4*)s;
  u16x4 o = { f2bf(f[0]), f2bf(f[1]), f2bf(f[2]), f2bf(f[3]) };
  *(u16x4*)&X[i] = o;
}

__global__ __launch_bounds__(256) void cast_f2b(
    const float* __restrict__ src, unsigned short* __restrict__ dst, int n) {
  int i = (blockIdx.x * 256 + threadIdx.x) * 4;
  if (i >= n) return;
  f32x4 f = *(const f32x4*)&src[i];
  u16x4 o = { f2bf(f[0]), f2bf(f[1]), f2bf(f[2]), f2bf(f[3]) };
  *(u16x4*)&dst[i] = o;
}

// ---------------- GEMM: C[M,N] = A[M,K] @ B[N,K]^T + bias ----------------
// EPI: 0 = f32 out, 1 = bf16 out, 2 = exact-GELU -> bf16 out
template<int EPI>
__global__ __launch_bounds__(256, 3) void gemm_bt(
    const unsigned short* __restrict__ A, const unsigned short* __restrict__ B,
    const float* __restrict__ bias, void* __restrict__ Cout,
    int M, int N, int K) {
  __shared__ __align__(16) unsigned short As[128 * 32];
  __shared__ __align__(16) unsigned short Bs[128 * 32];
  const int tid = threadIdx.x;
  const int w = tid >> 6, l = tid & 63;
  const int lr = l & 15, lg = l >> 4;
  const int bm = blockIdx.x * 128, bn = blockIdx.y * 128;
  const int wm = (w >> 1) * 64, wn = (w & 1) * 64;
  const unsigned short* Ath = A + (size_t)(bm + (tid >> 2)) * K + (tid & 3) * 8;
  const unsigned short* Bth = B + (size_t)(bn + (tid >> 2)) * K + (tid & 3) * 8;
  unsigned short* AsW = As + w * 512;
  unsigned short* BsW = Bs + w * 512;
  const size_t rstep = (size_t)64 * K;
  f32x4 acc[4][4] = {};
  for (int k0 = 0; k0 < K; k0 += 32) {
    gld_lds16(AsW,        Ath + k0);
    gld_lds16(AsW + 2048, Ath + k0 + rstep);
    gld_lds16(BsW,        Bth + k0);
    gld_lds16(BsW + 2048, Bth + k0 + rstep);
    __syncthreads();
    bf16x8 af[4], bfr[4];
#pragma unroll
    for (int mt = 0; mt < 4; ++mt)
      af[mt] = *(const bf16x8*)&As[(wm + mt * 16 + lr) * 32 + lg * 8];
#pragma unroll
    for (int nt = 0; nt < 4; ++nt)
      bfr[nt] = *(const bf16x8*)&Bs[(wn + nt * 16 + lr) * 32 + lg * 8];
#pragma unroll
    for (int mt = 0; mt < 4; ++mt)
#pragma unroll
      for (int nt = 0; nt < 4; ++nt)
        acc[mt][nt] = mfma16(af[mt], bfr[nt], acc[mt][nt]);
    __syncthreads();
  }
#pragma unroll
  for (int mt = 0; mt < 4; ++mt) {
    int row0 = bm + wm + mt * 16 + lg * 4;
#pragma unroll
    for (int nt = 0; nt < 4; ++nt) {
      int col = bn + wn + nt * 16 + lr;
      float bcol = bias[col];
#pragma unroll
      for (int r = 0; r < 4; ++r) {
        float vv = acc[mt][nt][r] + bcol;
        if (EPI == 2) vv = 0.5f * vv * (1.0f + erff(vv * 0.70710678118654752f));
        if (EPI == 0)
          ((float*)Cout)[(size_t)(row0 + r) * N + col] = vv;
        else
          ((unsigned short*)Cout)[(size_t)(row0 + r) * N + col] = f2bf(vv);
      }
    }
  }
}

// ---------------- causal flash attention, no softmax scale ----------------
// grid: (NB*NH, SEQ/128). 4 waves, each owns 32 q-rows. head_dim = 64.
__global__ __launch_bounds__(256, 2) void attn_kernel(
    const unsigned short* __restrict__ Q, const unsigned short* __restrict__ K,
    const unsigned short* __restrict__ V, unsigned short* __restrict__ O) {
  __shared__ __align__(16) unsigned short Ks[64 * KPAD];
  __shared__ __align__(16) unsigned short Vt[64 * KPAD];
  __shared__ __align__(16) unsigned short Ps[4][32 * KPAD];
  const int tid = threadIdx.x;
  const int w = tid >> 6, l = tid & 63;
  const int lr = l & 15, lg = l >> 4;
  const int bh = blockIdx.x;
  const int b = bh >> 4, h = bh & 15;
  const int qblk = blockIdx.y;
  const int q0 = qblk * 128 + w * 32;
  const size_t tok0 = (size_t)b * SEQ;
  const size_t hoff = (size_t)h * 64;

  bf16x8 qf[2][2];
#pragma unroll
  for (int mt = 0; mt < 2; ++mt)
#pragma unroll
    for (int ks = 0; ks < 2; ++ks)
      qf[mt][ks] = *(const bf16x8*)&Q[(tok0 + q0 + mt * 16 + lr) * DM + hoff + ks * 32 + lg * 8];

  f32x4 o[2][4] = {};
  float mrun[2][4], lrun[2][4];
#pragma unroll
  for (int mt = 0; mt < 2; ++mt)
#pragma unroll
    for (int r = 0; r < 4; ++r) { mrun[mt][r] = -3.0e38f; lrun[mt][r] = 0.f; }

  const int jmax = qblk * 2 + 1;
  for (int j = 0; j <= jmax; ++j) {
    const int k0 = j * 64;
    // stage K (row-major, padded) and V (transposed) tiles
#pragma unroll
    for (int cc = 0; cc < 2; ++cc) {
      int c = tid + cc * 256;
      int r = c >> 3, c8 = (c & 7) * 8;
      size_t grow = (tok0 + k0 + r) * DM + hoff + c8;
      u16x8 kv = *(const u16x8*)&K[grow];
      *(u16x8*)&Ks[r * KPAD + c8] = kv;
      u16x8 vv = *(const u16x8*)&V[grow];
#pragma unroll
      for (int ii = 0; ii < 8; ++ii) Vt[(c8 + ii) * KPAD + r] = vv[ii];
    }
    __syncthreads();
    if (k0 <= q0 + 31) {
      f32x4 s[2][4] = {};
#pragma unroll
      for (int nt = 0; nt < 4; ++nt)
#pragma unroll
        for (int ks = 0; ks < 2; ++ks) {
          bf16x8 kb = *(const bf16x8*)&Ks[(nt * 16 + lr) * KPAD + ks * 32 + lg * 8];
#pragma unroll
          for (int mt = 0; mt < 2; ++mt)
            s[mt][nt] = mfma16(qf[mt][ks], kb, s[mt][nt]);
        }
      if (k0 + 63 > q0) {  // diagonal tile: apply causal mask
#pragma unroll
        for (int mt = 0; mt < 2; ++mt)
#pragma unroll
          for (int nt = 0; nt < 4; ++nt) {
            int kg = k0 + nt * 16 + lr;
#pragma unroll
            for (int r = 0; r < 4; ++r) {
              int qg = q0 + mt * 16 + lg * 4 + r;
              if (kg > qg) s[mt][nt][r] = -3.0e38f;
            }
          }
      }
#pragma unroll
      for (int mt = 0; mt < 2; ++mt)
#pragma unroll
        for (int r = 0; r < 4; ++r) {
          float mx = fmaxf(fmaxf(s[mt][0][r], s[mt][1][r]),
                           fmaxf(s[mt][2][r], s[mt][3][r]));
          mx = fmaxf(mx, __shfl_xor(mx, 1, 64));
          mx = fmaxf(mx, __shfl_xor(mx, 2, 64));
          mx = fmaxf(mx, __shfl_xor(mx, 4, 64));
          mx = fmaxf(mx, __shfl_xor(mx, 8, 64));
          float mnew = fmaxf(mrun[mt][r], mx);
          float sc = __expf(mrun[mt][r] - mnew);
          float rs = 0.f;
#pragma unroll
          for (int nt = 0; nt < 4; ++nt) {
            float p = __expf(s[mt][nt][r] - mnew);
            s[mt][nt][r] = p;
            rs += p;
          }
          rs += __shfl_xor(rs, 1, 64);
          rs += __shfl_xor(rs, 2, 64);
          rs += __shfl_xor(rs, 4, 64);
          rs += __shfl_xor(rs, 8, 64);
          lrun[mt][r] = lrun[mt][r] * sc + rs;
          mrun[mt][r] = mnew;
#pragma unroll
          for (int dt = 0; dt < 4; ++dt) o[mt][dt][r] *= sc;
          int prow = mt * 16 + lg * 4 + r;
#pragma unroll
          for (int nt = 0; nt < 4; ++nt)
            Ps[w][prow * KPAD + nt * 16 + lr] = f2bf(s[mt][nt][r]);
        }
      asm volatile("s_waitcnt lgkmcnt(0)" ::: "memory");
      __builtin_amdgcn_sched_barrier(0);
#pragma unroll
      for (int ks = 0; ks < 2; ++ks) {
        bf16x8 pa[2];
#pragma unroll
        for (int mt = 0; mt < 2; ++mt)
          pa[mt] = *(const bf16x8*)&Ps[w][(mt * 16 + lr) * KPAD + ks * 32 + lg * 8];
#pragma unroll
        for (int dt = 0; dt < 4; ++dt) {
          bf16x8 vb = *(const bf16x8*)&Vt[(dt * 16 + lr) * KPAD + ks * 32 + lg * 8];
#pragma unroll
          for (int mt = 0; mt < 2; ++mt)
            o[mt][dt] = mfma16(pa[mt], vb, o[mt][dt]);
        }
      }
    }
    __syncthreads();
  }
#pragma unroll
  for (int mt = 0; mt < 2; ++mt)
#pragma unroll
    for (int r = 0; r < 4; ++r) {
      float inv = 1.0f / lrun[mt][r];
      size_t row = tok0 + q0 + mt * 16 + lg * 4 + r;
#pragma unroll
      for (int dt = 0; dt < 4; ++dt)
        O[row * DM + hoff + dt * 16 + lr] = f2bf(o[mt][dt][r] * inv);
    }
}

// ---------------- fused residual + LayerNorm ----------------
// MODE 0: x = bf16(Xa) + bf16(Xc) -> bf16 out.  MODE 1: x = bf16(Xa) + f32(Xc) -> f32 out.
template<int MODE>
__global__ __launch_bounds__(256) void ln_kernel(
    const unsigned short* __restrict__ Xa, const void* __restrict__ Xc,
    const float* __restrict__ g, const float* __restrict__ be,
    void* __restrict__ outp) {
  const int row = blockIdx.x, t = threadIdx.x;
  const size_t base = (size_t)row * DM + t * 4;
  float x[4];
  u16x4 a = *(const u16x4*)&Xa[base];
  if (MODE == 0) {
    u16x4 c = *(const u16x4*)&((const unsigned short*)Xc)[base];
#pragma unroll
    for (int i = 0; i < 4; ++i) x[i] = bf2f(a[i]) + bf2f(c[i]);
  } else {
    f32x4 c = *(const f32x4*)&((const float*)Xc)[base];
#pragma unroll
    for (int i = 0; i < 4; ++i) x[i] = bf2f(a[i]) + c[i];
  }
  float s = x[0] + x[1] + x[2] + x[3];
  float ss = x[0] * x[0] + x[1] * x[1] + x[2] * x[2] + x[3] * x[3];
#pragma unroll
  for (int m = 1; m < 64; m <<= 1) {
    s  += __shfl_xor(s, m, 64);
    ss += __shfl_xor(ss, m, 64);
  }
  __shared__ float red[8];
  const int w = t >> 6;
  if ((t & 63) == 0) { red[w * 2] = s; red[w * 2 + 1] = ss; }
  __syncthreads();
  s  = red[0] + red[2] + red[4] + red[6];
  ss = red[1] + red[3] + red[5] + red[7];
  const float mean = s * (1.0f / DM);
  const float var = ss * (1.0f / DM) - mean * mean;
  const float rstd = rsqrtf(var + 1e-5f);
  if (MODE == 0) {
    u16x4 o;
#pragma unroll
    for (int i = 0; i < 4; ++i) {
      int cx = t * 4 + i;
      o[i] = f2bf((x[i] - mean) * rstd * g[cx] + be[cx]);
    }
    *(u16x4*)&((unsigned short*)outp)[base] = o;
  } else {
    f32x4 o;
#pragma unroll
    for (int i = 0; i < 4; ++i) {
      int cx = t * 4 + i;
      o[i] = (x[i] - mean) * rstd * g[cx] + be[cx];
    }
    *(f32x4*)&((float*)outp)[base] = o;
  }
}

extern "C" void kernel_launch(void* const* d_in, const int* in_sizes, int n_in,
                              void* d_out, int out_size, void* d_ws, size_t ws_size,
                              hipStream_t stream) {
  (void)in_sizes; (void)n_in; (void)out_size; (void)ws_size;
  const float* kq  = (const float*)d_in[0];
  const float* v   = (const float*)d_in[1];
  const float* Wk  = (const float*)d_in[2];
  const float* bk  = (const float*)d_in[3];
  const float* Wq  = (const float*)d_in[4];
  const float* bq  = (const float*)d_in[5];
  const float* Wv  = (const float*)d_in[6];
  const float* bv  = (const float*)d_in[7];
  const float* W1  = (const float*)d_in[8];
  const float* b1  = (const float*)d_in[9];
  const float* W2  = (const float*)d_in[10];
  const float* b2  = (const float*)d_in[11];
  const float* g1  = (const float*)d_in[12];
  const float* be1 = (const float*)d_in[13];
  const float* g2  = (const float*)d_in[14];
  const float* be2 = (const float*)d_in[15];
  float* out = (float*)d_out;
  uint8_t* ws = (uint8_t*)d_ws;

  // Workspace overlay (lifetimes):  region A [0, 73.4MB) holds X/Wqkv/Q/K/attn
  // which are all dead before FFN1; F1b reuses it.
  unsigned short* Xb  = (unsigned short*)(ws + 0);
  unsigned short* Wkb = (unsigned short*)(ws + 16777216);
  unsigned short* Wqb = (unsigned short*)(ws + 18874368);
  unsigned short* Wvb = (unsigned short*)(ws + 20971520);
  unsigned short* Qb  = (unsigned short*)(ws + 23068672);
  unsigned short* Kb  = (unsigned short*)(ws + 39845888);
  unsigned short* Ab  = (unsigned short*)(ws + 56623104);
  unsigned short* F1b = (unsigned short*)(ws + 0);          // overlay
  unsigned short* W1b = (unsigned short*)(ws + 73400320);
  unsigned short* W2b = (unsigned short*)(ws + 81788928);
  unsigned short* Vb  = (unsigned short*)(ws + 90177536);
  unsigned short* Hb  = (unsigned short*)(ws + 106954752);
  float*          F2f = (float*)(ws + 123731968);

  concat_cast<<<TOK * DM / 1024, 256, 0, stream>>>(kq, v, Xb);
  cast_f2b<<<1024, 256, 0, stream>>>(Wk, Wkb, DM * DM);
  cast_f2b<<<1024, 256, 0, stream>>>(Wq, Wqb, DM * DM);
  cast_f2b<<<1024, 256, 0, stream>>>(Wv, Wvb, DM * DM);
  cast_f2b<<<4096, 256, 0, stream>>>(W1, W1b, FFD * DM);
  cast_f2b<<<4096, 256, 0, stream>>>(W2, W2b, DM * FFD);

  gemm_bt<1><<<dim3(64, 8), 256, 0, stream>>>(Xb, Wkb, bk, Kb, TOK, DM, DM);
  gemm_bt<1><<<dim3(64, 8), 256, 0, stream>>>(Xb, Wqb, bq, Qb, TOK, DM, DM);
  gemm_bt<1><<<dim3(64, 8), 256, 0, stream>>>(Xb, Wvb, bv, Vb, TOK, DM, DM);

  attn_kernel<<<dim3(64, 16), 256, 0, stream>>>(Qb, Kb, Vb, Ab);

  ln_kernel<0><<<TOK, 256, 0, stream>>>(Vb, Ab, g1, be1, Hb);

  gemm_bt<2><<<dim3(64, 32), 256, 0, stream>>>(Hb, W1b, b1, F1b, TOK, FFD, DM);
  gemm_bt<0><<<dim3(64, 8), 256, 0, stream>>>(F1b, W2b, b2, F2f, TOK, DM, FFD);

  ln_kernel<1><<<TOK, 256, 0, stream>>>(Hb, F2f, g2, be2, out);
}